// Round 12
// baseline (179.349 us; speedup 1.0000x reference)
//
#include <hip/hip_runtime.h>

// ---------- types / helpers ----------
typedef __attribute__((ext_vector_type(8))) short short8;          // 8 x bf16 bits - MFMA A/B frag
typedef __attribute__((ext_vector_type(4))) float f32x4;           // MFMA C/D frag
typedef __attribute__((ext_vector_type(8))) unsigned short ushort8;

typedef const unsigned int __attribute__((address_space(1)))* gas1_t;
typedef unsigned int __attribute__((address_space(3)))* las3_t;

__device__ __forceinline__ void gload_lds16(const void* g, void* l) {
  // async global->LDS, 16B per lane. LDS dest must be wave-uniform base + lane*16.
  __builtin_amdgcn_global_load_lds((gas1_t)g, (las3_t)l, 16, 0, 0);
}

__device__ __forceinline__ unsigned short f2bf(float f) {
  unsigned int u = __float_as_uint(f);
  u += 0x7FFFu + ((u >> 16) & 1u);
  return (unsigned short)(u >> 16);
}
__device__ __forceinline__ float bf2f(unsigned short b) {
  return __uint_as_float(((unsigned int)b) << 16);
}

// ---------- fp32 -> bf16 convert (x) ----------
__global__ __launch_bounds__(256) void conv_f32_bf16(const float* __restrict__ in,
                                                     unsigned short* __restrict__ out, int n8) {
  int i = blockIdx.x * 256 + threadIdx.x;
  if (i >= n8) return;
  const f32x4* p = (const f32x4*)(in + (size_t)i * 8);
  f32x4 a = p[0], b = p[1];
  ushort8 o;
  o[0]=f2bf(a[0]); o[1]=f2bf(a[1]); o[2]=f2bf(a[2]); o[3]=f2bf(a[3]);
  o[4]=f2bf(b[0]); o[5]=f2bf(b[1]); o[6]=f2bf(b[2]); o[7]=f2bf(b[3]);
  *(ushort8*)(out + (size_t)i * 8) = o;
}

// ---------- transpose+convert W (1024x1024 fp32) -> Wt bf16, 3 matrices ----------
__global__ __launch_bounds__(256) void transconv_w(const float* __restrict__ Wq,
                                                   const float* __restrict__ Wk,
                                                   const float* __restrict__ Wv,
                                                   unsigned short* __restrict__ out) {
  __shared__ unsigned short tile[64][66];
  const float* W = (blockIdx.z == 0) ? Wq : ((blockIdx.z == 1) ? Wk : Wv);
  unsigned short* O = out + (size_t)blockIdx.z * 1048576;
  const int bi = blockIdx.x * 64;
  const int bo = blockIdx.y * 64;
#pragma unroll
  for (int p = 0; p < 16; ++p) {
    int idx = p * 256 + threadIdx.x;
    int r = idx >> 6, c = idx & 63;
    tile[r][c] = f2bf(W[(size_t)(bi + r) * 1024 + bo + c]);
  }
  __syncthreads();
#pragma unroll
  for (int p = 0; p < 16; ++p) {
    int idx = p * 256 + threadIdx.x;
    int r = idx >> 6, c = idx & 63;
    O[(size_t)(bo + r) * 1024 + bi + c] = tile[c][r];
  }
}

// ---------- transpose bf16 [R][C] -> [C][R] (for v -> vt) ----------
__global__ __launch_bounds__(256) void trans_bf16(const unsigned short* __restrict__ in,
                                                  unsigned short* __restrict__ out, int R, int C) {
  __shared__ unsigned short tile[64][66];
  const int br = blockIdx.x * 64, bc = blockIdx.y * 64;
#pragma unroll
  for (int p = 0; p < 16; ++p) {
    int idx = p * 256 + threadIdx.x;
    int r = idx >> 6, c = idx & 63;
    tile[r][c] = in[(size_t)(br + r) * C + bc + c];
  }
  __syncthreads();
#pragma unroll
  for (int p = 0; p < 16; ++p) {
    int idx = p * 256 + threadIdx.x;
    int r = idx >> 6, c = idx & 63;
    out[(size_t)(bc + r) * R + br + c] = tile[c][r];
  }
}

// ---------- reduce split-K partials: out[m][d] = (sum_z P[z][m][d]) / rsum[m] ----------
__global__ __launch_bounds__(256) void reduce_pv(const unsigned short* __restrict__ P,
                                                 const float* __restrict__ rsum,
                                                 float* __restrict__ out) {
  int i = blockIdx.x * 256 + threadIdx.x;
  const int m = (i * 8) >> 10;
  const float inv = 1.0f / rsum[m];
  float s[8] = {0.f, 0.f, 0.f, 0.f, 0.f, 0.f, 0.f, 0.f};
#pragma unroll
  for (int z = 0; z < 4; ++z) {
    ushort8 v = *(const ushort8*)(P + (size_t)z * 4194304 + (size_t)i * 8);
#pragma unroll
    for (int j = 0; j < 8; ++j) s[j] += bf2f(v[j]);
  }
  f32x4 o0, o1;
#pragma unroll
  for (int j = 0; j < 4; ++j) { o0[j] = s[j] * inv; o1[j] = s[4 + j] * inv; }
  f32x4* po = (f32x4*)(out + (size_t)i * 8);
  po[0] = o0; po[1] = o1;
}

// ---------- bf16 GEMM, B^T convention: C[m][n] = sum_k A[m][k]*B[n][k] ----------
// R12 = R5 (best: 150.9us) with ONE structural change: TRIPLE-buffer ring +
// counted vmcnt + bare s_barrier. R5's __syncthreads() emits a full
// vmcnt(0) drain each K-step, exposing the latency of the prefetch issued only
// ~300cy earlier (the measured ~2400cy/K-step). Here: STAGE(t+2) issued at
// iter t, vmcnt(4) retires only t+1's loads (t+2's 4 stay in flight across the
// barrier = ~2 K-steps of latency cover). Ring safety: iter t's STAGE
// overwrites the buffer last READ at t-1; the t-1 barrier orders all waves'
// reads (consumed by MFMA) before any wave issues iter-t staging.
// LDS 48KB -> 3 blocks/CU (R8's counted scheme had 1 block/CU - no TLP; R5 had
// TLP but drains. This is the untested combination.)
// EPI: 0 = +bias -> bf16 (QKV, z = matrix)  1 = exp(s*scale)+rowsum -> bf16
//      2 = split-K PV (z = K-slice): plain bf16 partial stores
template <int BM, int BN, int MI, int NI, int EPI>
__global__ __launch_bounds__(256, 3) void gemm_bt(
    const unsigned short* __restrict__ A, const unsigned short* __restrict__ B,
    int lda, int ldb, int K, void* __restrict__ C, int ldc,
    size_t strideBz, size_t strideCz,
    const float* __restrict__ bq, const float* __restrict__ bk, const float* __restrict__ bv,
    float scale, float* __restrict__ rsum) {
  static_assert(BM == 2 * MI * 16 && BN == 2 * NI * 16, "tile mismatch");
  __shared__ unsigned short As[3][BM * 32];
  __shared__ unsigned short Bs[3][BN * 32];
  const int tid = threadIdx.x;
  const int lane = tid & 63;
  const int w = tid >> 6;
  const int wr = w >> 1, wc = w & 1;

  // bijective XCD swizzle (nwg % 8 == 0 for all our grids)
  const int nwgx = gridDim.x;
  const int nwg = nwgx * gridDim.y;
  const int lin = blockIdx.y * nwgx + blockIdx.x;
  const int swz = (lin & 7) * (nwg >> 3) + (lin >> 3);
  const int m0 = (swz / nwgx) * BM;
  const int n0 = (swz % nwgx) * BN;
  const int z = blockIdx.z;
  const unsigned short* Bz = B + (size_t)z * strideBz;
  const size_t koff = (EPI == 2) ? (size_t)z * K : 0;

  f32x4 acc[MI][NI];
#pragma unroll
  for (int i = 0; i < MI; ++i)
#pragma unroll
    for (int j = 0; j < NI; ++j) acc[i][j] = f32x4{0.f, 0.f, 0.f, 0.f};

  const int l16 = lane & 15;
  const int kh = (lane >> 4) << 3;  // k-offset 0/8/16/24 within BK=32

  // persistent per-thread staging source pointers
  const unsigned short* aptr[BM / 64];
  const unsigned short* bptr[BN / 64];
#pragma unroll
  for (int i = 0; i < BM / 64; ++i) {
    int t = i * 256 + tid;
    aptr[i] = A + (size_t)(m0 + (t >> 2)) * lda + koff + (t & 3) * 8;
  }
#pragma unroll
  for (int i = 0; i < BN / 64; ++i) {
    int t = i * 256 + tid;
    bptr[i] = Bz + (size_t)(n0 + (t >> 2)) * ldb + koff + (t & 3) * 8;
  }

// hygienic internals (_si/_st): k0 expands at call site only.
// 4 gload_lds per thread per STAGE (BM/64 + BN/64 = 2 + 2).
#define STAGE(buf, k0)                                                        \
  do {                                                                        \
    _Pragma("unroll") for (int _si = 0; _si < BM / 64; ++_si) {               \
      const int _st = _si * 256 + tid;                                        \
      gload_lds16(aptr[_si] + (k0), &As[buf][_st * 8]);                       \
    }                                                                         \
    _Pragma("unroll") for (int _si = 0; _si < BN / 64; ++_si) {               \
      const int _st = _si * 256 + tid;                                        \
      gload_lds16(bptr[_si] + (k0), &Bs[buf][_st * 8]);                       \
    }                                                                         \
  } while (0)

  const int NT = K / 32;  // NT = 32 for all our launches (>= 3 required)
  // prologue: tiles t0 -> buf0, t1 -> buf1 (8 loads outstanding)
  STAGE(0, 0);
  STAGE(1, 32);
  asm volatile("s_waitcnt vmcnt(4)" ::: "memory");  // t0 landed; t1's 4 in flight
  asm volatile("s_barrier" ::: "memory");

  int c0 = 0, c2 = 2;  // current read buf / staging target buf
  for (int t = 0; t < NT; ++t) {
    if (t + 2 < NT) STAGE(c2, (t + 2) * 32);  // overwrite buf last read at t-1
    short8 a[MI], b[NI];
#pragma unroll
    for (int mi = 0; mi < MI; ++mi)
      a[mi] = *(const short8*)(&As[c0][(wr * (MI * 16) + mi * 16 + l16) * 32 + kh]);
#pragma unroll
    for (int ni = 0; ni < NI; ++ni)
      b[ni] = *(const short8*)(&Bs[c0][(wc * (NI * 16) + ni * 16 + l16) * 32 + kh]);
#pragma unroll
    for (int mi = 0; mi < MI; ++mi)
#pragma unroll
      for (int ni = 0; ni < NI; ++ni)
        acc[mi][ni] = __builtin_amdgcn_mfma_f32_16x16x32_bf16(a[mi], b[ni], acc[mi][ni], 0, 0, 0);
    // counted wait: retire t+1's 4 loads, keep t+2's 4 in flight (never drain mid-loop)
    if (t + 2 < NT)      asm volatile("s_waitcnt vmcnt(4)" ::: "memory");
    else if (t + 1 < NT) asm volatile("s_waitcnt vmcnt(0)" ::: "memory");
    asm volatile("s_barrier" ::: "memory");
    c0 = (c0 == 2) ? 0 : c0 + 1;
    c2 = (c2 == 2) ? 0 : c2 + 1;
  }
#undef STAGE

  // epilogue: C/D layout col = lane&15, row = (lane>>4)*4 + r
  const int row0 = m0 + wr * (MI * 16) + ((lane >> 4) << 2);
  const int col0 = n0 + wc * (NI * 16);

  if constexpr (EPI == 0) {
    unsigned short* O = (unsigned short*)C + (size_t)z * strideCz;
    const float* bias = (z == 0) ? bq : ((z == 1) ? bk : bv);
#pragma unroll
    for (int mi = 0; mi < MI; ++mi)
#pragma unroll
      for (int ni = 0; ni < NI; ++ni) {
        const int col = col0 + ni * 16 + l16;
        const int row = row0 + mi * 16;
        float bvv = bias[col];
#pragma unroll
        for (int r = 0; r < 4; ++r)
          O[(size_t)(row + r) * ldc + col] = f2bf(acc[mi][ni][r] + bvv);
      }
  } else if constexpr (EPI == 1) {
    // exp epilogue + fused row-sum of the bf16-ROUNDED values (what PV consumes)
    unsigned short* O = (unsigned short*)C;
#pragma unroll
    for (int mi = 0; mi < MI; ++mi) {
      float rs[4] = {0.f, 0.f, 0.f, 0.f};
      const int row = row0 + mi * 16;
#pragma unroll
      for (int ni = 0; ni < NI; ++ni) {
        const int col = col0 + ni * 16 + l16;
#pragma unroll
        for (int r = 0; r < 4; ++r) {
          unsigned short ub = f2bf(__expf(acc[mi][ni][r] * scale));
          O[(size_t)(row + r) * ldc + col] = ub;
          rs[r] += bf2f(ub);
        }
      }
#pragma unroll
      for (int off = 1; off <= 8; off <<= 1) {
#pragma unroll
        for (int r = 0; r < 4; ++r) rs[r] += __shfl_xor(rs[r], off);
      }
      if (l16 == 0) {
#pragma unroll
        for (int r = 0; r < 4; ++r) unsafeAtomicAdd(&rsum[row + r], rs[r]);
      }
    }
  } else {
    // split-K PV: plain bf16 stores of the slice partial
    unsigned short* O = (unsigned short*)C + (size_t)z * strideCz;
#pragma unroll
    for (int mi = 0; mi < MI; ++mi)
#pragma unroll
      for (int ni = 0; ni < NI; ++ni) {
        const int col = col0 + ni * 16 + l16;
        const int row = row0 + mi * 16;
#pragma unroll
        for (int r = 0; r < 4; ++r)
          O[(size_t)(row + r) * ldc + col] = f2bf(acc[mi][ni][r]);
      }
  }
}

// ---------- launch ----------
extern "C" void kernel_launch(void* const* d_in, const int* in_sizes, int n_in,
                              void* d_out, int out_size, void* d_ws, size_t ws_size,
                              hipStream_t stream) {
  const float* x  = (const float*)d_in[0];
  const float* Wq = (const float*)d_in[1];
  const float* bq = (const float*)d_in[2];
  const float* Wk = (const float*)d_in[3];
  const float* bk = (const float*)d_in[4];
  const float* Wv = (const float*)d_in[5];
  const float* bv = (const float*)d_in[6];
  float* out = (float*)d_out;
  char* ws = (char*)d_ws;
  const size_t MB = 1024 * 1024;

  // ws layout (78 MB). Phase A: xb 0-8 | wt 8-14 | qkv 14-38 | vt 38-46 | S 46-78
  //                    Phase B (PV): P 0-32 (xb/wt/qb/kb/vb-head dead) | rsum@37 | vt | S
  unsigned short* xb  = (unsigned short*)(ws + 0);
  unsigned short* wt  = (unsigned short*)(ws + 8 * MB);
  unsigned short* qkv = (unsigned short*)(ws + 14 * MB);
  unsigned short* qb  = qkv;
  unsigned short* kb  = qkv + (size_t)4194304;
  unsigned short* vb  = qkv + (size_t)2 * 4194304;
  float*          rsum= (float*)(ws + 37 * MB);
  unsigned short* vt  = (unsigned short*)(ws + 38 * MB);
  unsigned short* S   = (unsigned short*)(ws + 46 * MB);
  unsigned short* P   = (unsigned short*)(ws + 0);

  // 1) convert x to bf16
  conv_f32_bf16<<<2048, 256, 0, stream>>>(x, xb, 524288);
  // 2) transpose+convert the three weight matrices
  transconv_w<<<dim3(16, 16, 3), 256, 0, stream>>>(Wq, Wk, Wv, wt);
  // 3) QKV projection: [4096,1024]x[1024,1024] x3, bias fused, bf16 out
  gemm_bt<128, 128, 4, 4, 0><<<dim3(8, 32, 3), 256, 0, stream>>>(
      xb, wt, 1024, 1024, 1024, qkv, 1024,
      (size_t)1048576, (size_t)4194304, bq, bk, bv, 1.0f, nullptr);
  // 4) transpose v -> vt
  trans_bf16<<<dim3(64, 16), 256, 0, stream>>>(vb, vt, 4096, 1024);
  // 4b) zero rsum (vb dead; rsum lives in its tail)
  hipMemsetAsync(rsum, 0, 4096 * sizeof(float), stream);
  // 5) E = exp(q k^T / 32), fused rsum accumulation (max-free: |s| <~ 2)
  gemm_bt<128, 128, 4, 4, 1><<<dim3(32, 32), 256, 0, stream>>>(
      qb, kb, 1024, 1024, 1024, S, 4096,
      (size_t)0, (size_t)0, nullptr, nullptr, nullptr, 0.03125f, rsum);
  // 6) PV split-K x4: P[z] = E[:, z*1024:+1024] @ v[z*1024:+1024, :]
  gemm_bt<128, 128, 4, 4, 2><<<dim3(8, 32, 4), 256, 0, stream>>>(
      S, vt, 4096, 4096, 1024, P, 1024,
      (size_t)0, (size_t)4194304, nullptr, nullptr, nullptr, 1.0f, nullptr);
  // 7) out = (sum_z P[z]) / rsum
  reduce_pv<<<2048, 256, 0, stream>>>(P, rsum, out);
}

// Round 13
// 151.076 us; speedup vs baseline: 1.1871x; 1.1871x over previous
//
#include <hip/hip_runtime.h>

// ---------- types / helpers ----------
typedef __attribute__((ext_vector_type(8))) short short8;          // 8 x bf16 bits - MFMA A/B frag
typedef __attribute__((ext_vector_type(4))) float f32x4;           // MFMA C/D frag
typedef __attribute__((ext_vector_type(8))) unsigned short ushort8;

typedef const unsigned int __attribute__((address_space(1)))* gas1_t;
typedef unsigned int __attribute__((address_space(3)))* las3_t;

__device__ __forceinline__ void gload_lds16(const void* g, void* l) {
  // async global->LDS, 16B per lane. LDS dest must be wave-uniform base + lane*16.
  __builtin_amdgcn_global_load_lds((gas1_t)g, (las3_t)l, 16, 0, 0);
}

__device__ __forceinline__ unsigned short f2bf(float f) {
  unsigned int u = __float_as_uint(f);
  u += 0x7FFFu + ((u >> 16) & 1u);
  return (unsigned short)(u >> 16);
}
__device__ __forceinline__ float bf2f(unsigned short b) {
  return __uint_as_float(((unsigned int)b) << 16);
}

// ---------- fp32 -> bf16 convert (x) ----------
__global__ __launch_bounds__(256) void conv_f32_bf16(const float* __restrict__ in,
                                                     unsigned short* __restrict__ out, int n8) {
  int i = blockIdx.x * 256 + threadIdx.x;
  if (i >= n8) return;
  const f32x4* p = (const f32x4*)(in + (size_t)i * 8);
  f32x4 a = p[0], b = p[1];
  ushort8 o;
  o[0]=f2bf(a[0]); o[1]=f2bf(a[1]); o[2]=f2bf(a[2]); o[3]=f2bf(a[3]);
  o[4]=f2bf(b[0]); o[5]=f2bf(b[1]); o[6]=f2bf(b[2]); o[7]=f2bf(b[3]);
  *(ushort8*)(out + (size_t)i * 8) = o;
}

// ---------- transpose+convert W (1024x1024 fp32) -> Wt bf16, 3 matrices ----------
__global__ __launch_bounds__(256) void transconv_w(const float* __restrict__ Wq,
                                                   const float* __restrict__ Wk,
                                                   const float* __restrict__ Wv,
                                                   unsigned short* __restrict__ out) {
  __shared__ unsigned short tile[64][66];
  const float* W = (blockIdx.z == 0) ? Wq : ((blockIdx.z == 1) ? Wk : Wv);
  unsigned short* O = out + (size_t)blockIdx.z * 1048576;
  const int bi = blockIdx.x * 64;  // d_in block
  const int bo = blockIdx.y * 64;  // d_out block
#pragma unroll
  for (int p = 0; p < 16; ++p) {
    int idx = p * 256 + threadIdx.x;
    int r = idx >> 6, c = idx & 63;
    tile[r][c] = f2bf(W[(size_t)(bi + r) * 1024 + bo + c]);
  }
  __syncthreads();
#pragma unroll
  for (int p = 0; p < 16; ++p) {
    int idx = p * 256 + threadIdx.x;
    int r = idx >> 6, c = idx & 63;
    O[(size_t)(bo + r) * 1024 + bi + c] = tile[c][r];  // O[o][i] = W[i][o]
  }
}

// ---------- transpose bf16 [R][C] -> [C][R] (for v -> vt) ----------
__global__ __launch_bounds__(256) void trans_bf16(const unsigned short* __restrict__ in,
                                                  unsigned short* __restrict__ out, int R, int C) {
  __shared__ unsigned short tile[64][66];
  const int br = blockIdx.x * 64, bc = blockIdx.y * 64;
#pragma unroll
  for (int p = 0; p < 16; ++p) {
    int idx = p * 256 + threadIdx.x;
    int r = idx >> 6, c = idx & 63;
    tile[r][c] = in[(size_t)(br + r) * C + bc + c];
  }
  __syncthreads();
#pragma unroll
  for (int p = 0; p < 16; ++p) {
    int idx = p * 256 + threadIdx.x;
    int r = idx >> 6, c = idx & 63;
    out[(size_t)(bc + r) * R + br + c] = tile[c][r];
  }
}

// ---------- reduce split-K partials: out[m][d] = (sum_z P[z][m][d]) / rsum[m] ----------
__global__ __launch_bounds__(256) void reduce_pv(const unsigned short* __restrict__ P,
                                                 const float* __restrict__ rsum,
                                                 float* __restrict__ out) {
  int i = blockIdx.x * 256 + threadIdx.x;  // chunk index, grid covers 524288 exactly
  const int m = (i * 8) >> 10;
  const float inv = 1.0f / rsum[m];
  float s[8] = {0.f, 0.f, 0.f, 0.f, 0.f, 0.f, 0.f, 0.f};
#pragma unroll
  for (int z = 0; z < 4; ++z) {
    ushort8 v = *(const ushort8*)(P + (size_t)z * 4194304 + (size_t)i * 8);
#pragma unroll
    for (int j = 0; j < 8; ++j) s[j] += bf2f(v[j]);
  }
  f32x4 o0, o1;
#pragma unroll
  for (int j = 0; j < 4; ++j) { o0[j] = s[j] * inv; o1[j] = s[4 + j] * inv; }
  f32x4* po = (f32x4*)(out + (size_t)i * 8);
  po[0] = o0; po[1] = o1;
}

// ---------- bf16 GEMM, B^T convention: C[m][n] = sum_k A[m][k]*B[n][k] ----------
// R13 = R5 EXACTLY (best known: 150.9us — 2-buffer, one __syncthreads per K-step,
// 128x128 tile, 4 waves 2x2, launch_bounds(256,2)) + ONE data-placement change:
// both-sides granule-XOR swizzle (rule 21).
//   R5's fragment read was an 8-way bank conflict (row stride 64B -> bank group
//   16*(r&1); lanes 0,2,..14 all in banks 4q..4q+3, distinct rows). 4.2M
//   conflict-cycles/dispatch ~= 7us/CU. Swizzle: LDS slot (row, g) holds source
//   granule g^(row&3); reads use granule q^(row&3). Rows 0..15 then occupy all
//   8 (half, granule) slots x exactly 2-way — free per m136. Coalescing
//   unchanged (permutation within each 64B row).
// EPI: 0 = +bias -> bf16 (QKV, z selects matrix)
//      1 = exp(s*scale) -> bf16, fused row-sum atomics into rsum (scores)
//      2 = split-K PV: z = K-slice, PLAIN bf16 stores to partials C + z*strideCz
template <int BM, int BN, int MI, int NI, int EPI>
__global__ __launch_bounds__(256, 2) void gemm_bt(
    const unsigned short* __restrict__ A, const unsigned short* __restrict__ B,
    int lda, int ldb, int K, void* __restrict__ C, int ldc,
    size_t strideBz, size_t strideCz,
    const float* __restrict__ bq, const float* __restrict__ bk, const float* __restrict__ bv,
    float scale, float* __restrict__ rsum) {
  static_assert(BM == 2 * MI * 16 && BN == 2 * NI * 16, "tile mismatch");
  __shared__ unsigned short As[2][BM * 32];
  __shared__ unsigned short Bs[2][BN * 32];
  const int tid = threadIdx.x;
  const int lane = tid & 63;
  const int w = tid >> 6;
  const int wr = w >> 1, wc = w & 1;

  // bijective XCD swizzle (nwg % 8 == 0 for all our grids)
  const int nwgx = gridDim.x;
  const int nwg = nwgx * gridDim.y;
  const int lin = blockIdx.y * nwgx + blockIdx.x;
  const int swz = (lin & 7) * (nwg >> 3) + (lin >> 3);
  const int m0 = (swz / nwgx) * BM;
  const int n0 = (swz % nwgx) * BN;
  const int z = blockIdx.z;
  const unsigned short* Bz = B + (size_t)z * strideBz;
  // split-K (EPI==2): z is the K-slice index, slices tile K contiguously
  const size_t koff = (EPI == 2) ? (size_t)z * K : 0;

  f32x4 acc[MI][NI];
#pragma unroll
  for (int i = 0; i < MI; ++i)
#pragma unroll
    for (int j = 0; j < NI; ++j) acc[i][j] = f32x4{0.f, 0.f, 0.f, 0.f};

  const int l16 = lane & 15;
  // swizzled read granule: source k-quarter q=(lane>>4) lives at LDS granule
  // q ^ (row&3); row&3 == l16&3 since all row bases are multiples of 16.
  const int khs = (((lane >> 4) ^ (l16 & 3)) << 3);  // element offset within 32-elem row

  // persistent per-thread staging source pointers, source-side granule XOR:
  // thread's LDS slot (row=t>>2, g=t&3) is filled from source granule g^(row&3)
  const unsigned short* aptr[BM / 64];
  const unsigned short* bptr[BN / 64];
#pragma unroll
  for (int i = 0; i < BM / 64; ++i) {
    int t = i * 256 + tid;
    int r = t >> 2;
    aptr[i] = A + (size_t)(m0 + r) * lda + koff + ((t & 3) ^ (r & 3)) * 8;
  }
#pragma unroll
  for (int i = 0; i < BN / 64; ++i) {
    int t = i * 256 + tid;
    int r = t >> 2;
    bptr[i] = Bz + (size_t)(n0 + r) * ldb + koff + ((t & 3) ^ (r & 3)) * 8;
  }

// hygienic internals (_si/_st): k0 expands at call site only
#define STAGE(buf, k0)                                                        \
  do {                                                                        \
    _Pragma("unroll") for (int _si = 0; _si < BM / 64; ++_si) {               \
      const int _st = _si * 256 + tid;                                        \
      gload_lds16(aptr[_si] + (k0), &As[buf][_st * 8]);                       \
    }                                                                         \
    _Pragma("unroll") for (int _si = 0; _si < BN / 64; ++_si) {               \
      const int _st = _si * 256 + tid;                                        \
      gload_lds16(bptr[_si] + (k0), &Bs[buf][_st * 8]);                       \
    }                                                                         \
  } while (0)

  STAGE(0, 0);
  __syncthreads();  // drains vmcnt(0) then barrier: buf0 ready for all waves

  const int NT = K / 32;
  for (int t = 0; t < NT; ++t) {
    const int cur = t & 1;
    if (t + 1 < NT) STAGE(cur ^ 1, (t + 1) * 32);  // async prefetch, overlaps compute
    short8 a[MI], b[NI];
#pragma unroll
    for (int mi = 0; mi < MI; ++mi)
      a[mi] = *(const short8*)(&As[cur][(wr * (MI * 16) + mi * 16 + l16) * 32 + khs]);
#pragma unroll
    for (int ni = 0; ni < NI; ++ni)
      b[ni] = *(const short8*)(&Bs[cur][(wc * (NI * 16) + ni * 16 + l16) * 32 + khs]);
#pragma unroll
    for (int mi = 0; mi < MI; ++mi)
#pragma unroll
      for (int ni = 0; ni < NI; ++ni)
        acc[mi][ni] = __builtin_amdgcn_mfma_f32_16x16x32_bf16(a[mi], b[ni], acc[mi][ni], 0, 0, 0);
    __syncthreads();  // one barrier/K-step: prefetch landed, cur free to overwrite
  }
#undef STAGE

  // epilogue: C/D layout col = lane&15, row = (lane>>4)*4 + r
  const int row0 = m0 + wr * (MI * 16) + ((lane >> 4) << 2);
  const int col0 = n0 + wc * (NI * 16);

  if constexpr (EPI == 0) {
    unsigned short* O = (unsigned short*)C + (size_t)z * strideCz;
    const float* bias = (z == 0) ? bq : ((z == 1) ? bk : bv);
#pragma unroll
    for (int mi = 0; mi < MI; ++mi)
#pragma unroll
      for (int ni = 0; ni < NI; ++ni) {
        const int col = col0 + ni * 16 + l16;
        const int row = row0 + mi * 16;
        float bvv = bias[col];
#pragma unroll
        for (int r = 0; r < 4; ++r)
          O[(size_t)(row + r) * ldc + col] = f2bf(acc[mi][ni][r] + bvv);
      }
  } else if constexpr (EPI == 1) {
    // exp epilogue + fused row-sum of the bf16-ROUNDED values (what PV consumes)
    unsigned short* O = (unsigned short*)C;
#pragma unroll
    for (int mi = 0; mi < MI; ++mi) {
      float rs[4] = {0.f, 0.f, 0.f, 0.f};
      const int row = row0 + mi * 16;
#pragma unroll
      for (int ni = 0; ni < NI; ++ni) {
        const int col = col0 + ni * 16 + l16;
#pragma unroll
        for (int r = 0; r < 4; ++r) {
          unsigned short ub = f2bf(__expf(acc[mi][ni][r] * scale));
          O[(size_t)(row + r) * ldc + col] = ub;
          rs[r] += bf2f(ub);
        }
      }
#pragma unroll
      for (int off = 1; off <= 8; off <<= 1) {
#pragma unroll
        for (int r = 0; r < 4; ++r) rs[r] += __shfl_xor(rs[r], off);
      }
      if (l16 == 0) {
#pragma unroll
        for (int r = 0; r < 4; ++r) unsafeAtomicAdd(&rsum[row + r], rs[r]);
      }
    }
  } else {
    // split-K PV: plain bf16 stores of the slice partial
    unsigned short* O = (unsigned short*)C + (size_t)z * strideCz;
#pragma unroll
    for (int mi = 0; mi < MI; ++mi)
#pragma unroll
      for (int ni = 0; ni < NI; ++ni) {
        const int col = col0 + ni * 16 + l16;
        const int row = row0 + mi * 16;
#pragma unroll
        for (int r = 0; r < 4; ++r)
          O[(size_t)(row + r) * ldc + col] = f2bf(acc[mi][ni][r]);
      }
  }
}

// ---------- launch ----------
extern "C" void kernel_launch(void* const* d_in, const int* in_sizes, int n_in,
                              void* d_out, int out_size, void* d_ws, size_t ws_size,
                              hipStream_t stream) {
  const float* x  = (const float*)d_in[0];
  const float* Wq = (const float*)d_in[1];
  const float* bq = (const float*)d_in[2];
  const float* Wk = (const float*)d_in[3];
  const float* bk = (const float*)d_in[4];
  const float* Wv = (const float*)d_in[5];
  const float* bv = (const float*)d_in[6];
  float* out = (float*)d_out;
  char* ws = (char*)d_ws;
  const size_t MB = 1024 * 1024;

  // ws layout (78 MB). Phase A: xb 0-8 | wt 8-14 | qkv 14-38 | vt 38-46 | S 46-78
  //                    Phase B (PV): P 0-32 (xb/wt/qb/kb/vb-head dead) | rsum@37 | vt | S
  unsigned short* xb  = (unsigned short*)(ws + 0);
  unsigned short* wt  = (unsigned short*)(ws + 8 * MB);
  unsigned short* qkv = (unsigned short*)(ws + 14 * MB);
  unsigned short* qb  = qkv;
  unsigned short* kb  = qkv + (size_t)4194304;
  unsigned short* vb  = qkv + (size_t)2 * 4194304;
  float*          rsum= (float*)(ws + 37 * MB);
  unsigned short* vt  = (unsigned short*)(ws + 38 * MB);
  unsigned short* S   = (unsigned short*)(ws + 46 * MB);
  unsigned short* P   = (unsigned short*)(ws + 0);

  // 1) convert x to bf16
  conv_f32_bf16<<<2048, 256, 0, stream>>>(x, xb, 524288);
  // 2) transpose+convert the three weight matrices
  transconv_w<<<dim3(16, 16, 3), 256, 0, stream>>>(Wq, Wk, Wv, wt);
  // 3) QKV projection: [4096,1024]x[1024,1024] x3, bias fused, bf16 out
  gemm_bt<128, 128, 4, 4, 0><<<dim3(8, 32, 3), 256, 0, stream>>>(
      xb, wt, 1024, 1024, 1024, qkv, 1024,
      (size_t)1048576, (size_t)4194304, bq, bk, bv, 1.0f, nullptr);
  // 4) transpose v -> vt
  trans_bf16<<<dim3(64, 16), 256, 0, stream>>>(vb, vt, 4096, 1024);
  // 4b) zero rsum (vb dead; rsum lives in its tail)
  hipMemsetAsync(rsum, 0, 4096 * sizeof(float), stream);
  // 5) E = exp(q k^T / 32), fused rsum accumulation (max-free: |s| <~ 2)
  gemm_bt<128, 128, 4, 4, 1><<<dim3(32, 32), 256, 0, stream>>>(
      qb, kb, 1024, 1024, 1024, S, 4096,
      (size_t)0, (size_t)0, nullptr, nullptr, nullptr, 0.03125f, rsum);
  // 6) PV split-K x4: P[z] = E[:, z*1024:+1024] @ v[z*1024:+1024, :]
  gemm_bt<128, 128, 4, 4, 2><<<dim3(8, 32, 4), 256, 0, stream>>>(
      S, vt, 4096, 4096, 1024, P, 1024,
      (size_t)0, (size_t)4194304, nullptr, nullptr, nullptr, 1.0f, nullptr);
  // 7) out = (sum_z P[z]) / rsum
  reduce_pv<<<2048, 256, 0, stream>>>(P, rsum, out);
}

// Round 14
// 149.169 us; speedup vs baseline: 1.2023x; 1.0128x over previous
//
#include <hip/hip_runtime.h>

// ---------- types / helpers ----------
typedef __attribute__((ext_vector_type(8))) short short8;          // 8 x bf16 bits - MFMA A/B frag
typedef __attribute__((ext_vector_type(4))) float f32x4;           // MFMA C/D frag
typedef __attribute__((ext_vector_type(8))) unsigned short ushort8;

typedef const unsigned int __attribute__((address_space(1)))* gas1_t;
typedef unsigned int __attribute__((address_space(3)))* las3_t;

__device__ __forceinline__ void gload_lds16(const void* g, void* l) {
  // async global->LDS, 16B per lane. LDS dest must be wave-uniform base + lane*16.
  __builtin_amdgcn_global_load_lds((gas1_t)g, (las3_t)l, 16, 0, 0);
}

__device__ __forceinline__ unsigned short f2bf(float f) {
  unsigned int u = __float_as_uint(f);
  u += 0x7FFFu + ((u >> 16) & 1u);
  return (unsigned short)(u >> 16);
}
__device__ __forceinline__ float bf2f(unsigned short b) {
  return __uint_as_float(((unsigned int)b) << 16);
}

// ---------- fp32 -> bf16 convert (x) ----------
__global__ __launch_bounds__(256) void conv_f32_bf16(const float* __restrict__ in,
                                                     unsigned short* __restrict__ out, int n8) {
  int i = blockIdx.x * 256 + threadIdx.x;
  if (i >= n8) return;
  const f32x4* p = (const f32x4*)(in + (size_t)i * 8);
  f32x4 a = p[0], b = p[1];
  ushort8 o;
  o[0]=f2bf(a[0]); o[1]=f2bf(a[1]); o[2]=f2bf(a[2]); o[3]=f2bf(a[3]);
  o[4]=f2bf(b[0]); o[5]=f2bf(b[1]); o[6]=f2bf(b[2]); o[7]=f2bf(b[3]);
  *(ushort8*)(out + (size_t)i * 8) = o;
}

// ---------- transpose+convert W (1024x1024 fp32) -> Wt bf16, 3 matrices ----------
__global__ __launch_bounds__(256) void transconv_w(const float* __restrict__ Wq,
                                                   const float* __restrict__ Wk,
                                                   const float* __restrict__ Wv,
                                                   unsigned short* __restrict__ out) {
  __shared__ unsigned short tile[64][66];
  const float* W = (blockIdx.z == 0) ? Wq : ((blockIdx.z == 1) ? Wk : Wv);
  unsigned short* O = out + (size_t)blockIdx.z * 1048576;
  const int bi = blockIdx.x * 64;  // d_in block
  const int bo = blockIdx.y * 64;  // d_out block
#pragma unroll
  for (int p = 0; p < 16; ++p) {
    int idx = p * 256 + threadIdx.x;
    int r = idx >> 6, c = idx & 63;
    tile[r][c] = f2bf(W[(size_t)(bi + r) * 1024 + bo + c]);
  }
  __syncthreads();
#pragma unroll
  for (int p = 0; p < 16; ++p) {
    int idx = p * 256 + threadIdx.x;
    int r = idx >> 6, c = idx & 63;
    O[(size_t)(bo + r) * 1024 + bi + c] = tile[c][r];  // O[o][i] = W[i][o]
  }
}

// ---------- transpose bf16 [R][C] -> [C][R] (for v -> vt) ----------
__global__ __launch_bounds__(256) void trans_bf16(const unsigned short* __restrict__ in,
                                                  unsigned short* __restrict__ out, int R, int C) {
  __shared__ unsigned short tile[64][66];
  const int br = blockIdx.x * 64, bc = blockIdx.y * 64;
#pragma unroll
  for (int p = 0; p < 16; ++p) {
    int idx = p * 256 + threadIdx.x;
    int r = idx >> 6, c = idx & 63;
    tile[r][c] = in[(size_t)(br + r) * C + bc + c];
  }
  __syncthreads();
#pragma unroll
  for (int p = 0; p < 16; ++p) {
    int idx = p * 256 + threadIdx.x;
    int r = idx >> 6, c = idx & 63;
    out[(size_t)(bc + r) * R + br + c] = tile[c][r];
  }
}

// ---------- reduce split-K partials: out[m][d] = (sum_z P[z][m][d]) / rsum[m] ----------
__global__ __launch_bounds__(256) void reduce_pv(const unsigned short* __restrict__ P,
                                                 const float* __restrict__ rsum,
                                                 float* __restrict__ out) {
  int i = blockIdx.x * 256 + threadIdx.x;  // chunk index, grid covers 524288 exactly
  const int m = (i * 8) >> 10;
  const float inv = 1.0f / rsum[m];
  float s[8] = {0.f, 0.f, 0.f, 0.f, 0.f, 0.f, 0.f, 0.f};
#pragma unroll
  for (int z = 0; z < 4; ++z) {
    ushort8 v = *(const ushort8*)(P + (size_t)z * 4194304 + (size_t)i * 8);
#pragma unroll
    for (int j = 0; j < 8; ++j) s[j] += bf2f(v[j]);
  }
  f32x4 o0, o1;
#pragma unroll
  for (int j = 0; j < 4; ++j) { o0[j] = s[j] * inv; o1[j] = s[4 + j] * inv; }
  f32x4* po = (f32x4*)(out + (size_t)i * 8);
  po[0] = o0; po[1] = o1;
}

// ---------- bf16 GEMM, B^T convention: C[m][n] = sum_k A[m][k]*B[n][k] ----------
// R14 = R13 body EXACTLY, ONE change: tile mapping. Chunked-XCD + 8x8 SUPER-BLOCK
// decode. Evidence: R13's SQ_LDS_BANK_CONFLICT == 2^22 exactly == 16 DMA-writes x
// 8 cyc x 32 steps x 1024 blocks -> conflicts are gload_lds write serialization
// (structural), reads were never conflicted. QKV streams 52 B/cyc/CU (~L2
// ceiling, m56) while QK^T runs 33 B/cyc: QK^T's old XCD working set = 4 m-rows
// x ALL 32 n-cols = 1+8 = 9MB >> 4MB L2 (B-panels thrash). 8x8 super-block =
// 2MB A + 2MB B = 4MB = exactly one XCD's L2. PV/QKV (nwgx=8) decode to the
// same footprint as before (already L2-fit) - unchanged by construction.
// EPI: 0 = +bias -> bf16 (QKV, z selects matrix)
//      1 = exp(s*scale) -> bf16, fused row-sum atomics into rsum (scores)
//      2 = split-K PV: z = K-slice, PLAIN bf16 stores to partials C + z*strideCz
template <int BM, int BN, int MI, int NI, int EPI>
__global__ __launch_bounds__(256, 2) void gemm_bt(
    const unsigned short* __restrict__ A, const unsigned short* __restrict__ B,
    int lda, int ldb, int K, void* __restrict__ C, int ldc,
    size_t strideBz, size_t strideCz,
    const float* __restrict__ bq, const float* __restrict__ bk, const float* __restrict__ bv,
    float scale, float* __restrict__ rsum) {
  static_assert(BM == 2 * MI * 16 && BN == 2 * NI * 16, "tile mismatch");
  __shared__ unsigned short As[2][BM * 32];
  __shared__ unsigned short Bs[2][BN * 32];
  const int tid = threadIdx.x;
  const int lane = tid & 63;
  const int w = tid >> 6;
  const int wr = w >> 1, wc = w & 1;

  // chunked XCD assignment + 8x8 super-block decode (nwg % 64 == 0 for all our
  // grids). XCD c owns contiguous p-range; consecutive p walk one 64-tile
  // super-block (4MB working set = one XCD L2) before moving on.
  const int nwgx = gridDim.x;
  const int nwg = nwgx * gridDim.y;
  const int lin = blockIdx.y * nwgx + blockIdx.x;
  const int p = (lin & 7) * (nwg >> 3) + (lin >> 3);
  const int nsbx = nwgx >> 3;                 // super-blocks per tile-row
  const int sb = p >> 6, wi = p & 63;
  const int sbr = sb / nsbx, sbc = sb - sbr * nsbx;
  const int m0 = (sbr * 8 + (wi >> 3)) * BM;
  const int n0 = (sbc * 8 + (wi & 7)) * BN;
  const int z = blockIdx.z;
  const unsigned short* Bz = B + (size_t)z * strideBz;
  // split-K (EPI==2): z is the K-slice index, slices tile K contiguously
  const size_t koff = (EPI == 2) ? (size_t)z * K : 0;

  f32x4 acc[MI][NI];
#pragma unroll
  for (int i = 0; i < MI; ++i)
#pragma unroll
    for (int j = 0; j < NI; ++j) acc[i][j] = f32x4{0.f, 0.f, 0.f, 0.f};

  const int l16 = lane & 15;
  // granule-XOR read offset (neutral vs R5, kept from R13)
  const int khs = (((lane >> 4) ^ (l16 & 3)) << 3);

  // persistent per-thread staging source pointers, source-side granule XOR
  const unsigned short* aptr[BM / 64];
  const unsigned short* bptr[BN / 64];
#pragma unroll
  for (int i = 0; i < BM / 64; ++i) {
    int t = i * 256 + tid;
    int r = t >> 2;
    aptr[i] = A + (size_t)(m0 + r) * lda + koff + ((t & 3) ^ (r & 3)) * 8;
  }
#pragma unroll
  for (int i = 0; i < BN / 64; ++i) {
    int t = i * 256 + tid;
    int r = t >> 2;
    bptr[i] = Bz + (size_t)(n0 + r) * ldb + koff + ((t & 3) ^ (r & 3)) * 8;
  }

// hygienic internals (_si/_st): k0 expands at call site only
#define STAGE(buf, k0)                                                        \
  do {                                                                        \
    _Pragma("unroll") for (int _si = 0; _si < BM / 64; ++_si) {               \
      const int _st = _si * 256 + tid;                                        \
      gload_lds16(aptr[_si] + (k0), &As[buf][_st * 8]);                       \
    }                                                                         \
    _Pragma("unroll") for (int _si = 0; _si < BN / 64; ++_si) {               \
      const int _st = _si * 256 + tid;                                        \
      gload_lds16(bptr[_si] + (k0), &Bs[buf][_st * 8]);                       \
    }                                                                         \
  } while (0)

  STAGE(0, 0);
  __syncthreads();  // drains vmcnt(0) then barrier: buf0 ready for all waves

  const int NT = K / 32;
  for (int t = 0; t < NT; ++t) {
    const int cur = t & 1;
    if (t + 1 < NT) STAGE(cur ^ 1, (t + 1) * 32);  // async prefetch, overlaps compute
    short8 a[MI], b[NI];
#pragma unroll
    for (int mi = 0; mi < MI; ++mi)
      a[mi] = *(const short8*)(&As[cur][(wr * (MI * 16) + mi * 16 + l16) * 32 + khs]);
#pragma unroll
    for (int ni = 0; ni < NI; ++ni)
      b[ni] = *(const short8*)(&Bs[cur][(wc * (NI * 16) + ni * 16 + l16) * 32 + khs]);
#pragma unroll
    for (int mi = 0; mi < MI; ++mi)
#pragma unroll
      for (int ni = 0; ni < NI; ++ni)
        acc[mi][ni] = __builtin_amdgcn_mfma_f32_16x16x32_bf16(a[mi], b[ni], acc[mi][ni], 0, 0, 0);
    __syncthreads();  // one barrier/K-step: prefetch landed, cur free to overwrite
  }
#undef STAGE

  // epilogue: C/D layout col = lane&15, row = (lane>>4)*4 + r
  const int row0 = m0 + wr * (MI * 16) + ((lane >> 4) << 2);
  const int col0 = n0 + wc * (NI * 16);

  if constexpr (EPI == 0) {
    unsigned short* O = (unsigned short*)C + (size_t)z * strideCz;
    const float* bias = (z == 0) ? bq : ((z == 1) ? bk : bv);
#pragma unroll
    for (int mi = 0; mi < MI; ++mi)
#pragma unroll
      for (int ni = 0; ni < NI; ++ni) {
        const int col = col0 + ni * 16 + l16;
        const int row = row0 + mi * 16;
        float bvv = bias[col];
#pragma unroll
        for (int r = 0; r < 4; ++r)
          O[(size_t)(row + r) * ldc + col] = f2bf(acc[mi][ni][r] + bvv);
      }
  } else if constexpr (EPI == 1) {
    // exp epilogue + fused row-sum of the bf16-ROUNDED values (what PV consumes)
    unsigned short* O = (unsigned short*)C;
#pragma unroll
    for (int mi = 0; mi < MI; ++mi) {
      float rs[4] = {0.f, 0.f, 0.f, 0.f};
      const int row = row0 + mi * 16;
#pragma unroll
      for (int ni = 0; ni < NI; ++ni) {
        const int col = col0 + ni * 16 + l16;
#pragma unroll
        for (int r = 0; r < 4; ++r) {
          unsigned short ub = f2bf(__expf(acc[mi][ni][r] * scale));
          O[(size_t)(row + r) * ldc + col] = ub;
          rs[r] += bf2f(ub);
        }
      }
#pragma unroll
      for (int off = 1; off <= 8; off <<= 1) {
#pragma unroll
        for (int r = 0; r < 4; ++r) rs[r] += __shfl_xor(rs[r], off);
      }
      if (l16 == 0) {
#pragma unroll
        for (int r = 0; r < 4; ++r) unsafeAtomicAdd(&rsum[row + r], rs[r]);
      }
    }
  } else {
    // split-K PV: plain bf16 stores of the slice partial
    unsigned short* O = (unsigned short*)C + (size_t)z * strideCz;
#pragma unroll
    for (int mi = 0; mi < MI; ++mi)
#pragma unroll
      for (int ni = 0; ni < NI; ++ni) {
        const int col = col0 + ni * 16 + l16;
        const int row = row0 + mi * 16;
#pragma unroll
        for (int r = 0; r < 4; ++r)
          O[(size_t)(row + r) * ldc + col] = f2bf(acc[mi][ni][r]);
      }
  }
}

// ---------- launch ----------
extern "C" void kernel_launch(void* const* d_in, const int* in_sizes, int n_in,
                              void* d_out, int out_size, void* d_ws, size_t ws_size,
                              hipStream_t stream) {
  const float* x  = (const float*)d_in[0];
  const float* Wq = (const float*)d_in[1];
  const float* bq = (const float*)d_in[2];
  const float* Wk = (const float*)d_in[3];
  const float* bk = (const float*)d_in[4];
  const float* Wv = (const float*)d_in[5];
  const float* bv = (const float*)d_in[6];
  float* out = (float*)d_out;
  char* ws = (char*)d_ws;
  const size_t MB = 1024 * 1024;

  // ws layout (78 MB). Phase A: xb 0-8 | wt 8-14 | qkv 14-38 | vt 38-46 | S 46-78
  //                    Phase B (PV): P 0-32 (xb/wt/qb/kb/vb-head dead) | rsum@37 | vt | S
  unsigned short* xb  = (unsigned short*)(ws + 0);
  unsigned short* wt  = (unsigned short*)(ws + 8 * MB);
  unsigned short* qkv = (unsigned short*)(ws + 14 * MB);
  unsigned short* qb  = qkv;
  unsigned short* kb  = qkv + (size_t)4194304;
  unsigned short* vb  = qkv + (size_t)2 * 4194304;
  float*          rsum= (float*)(ws + 37 * MB);
  unsigned short* vt  = (unsigned short*)(ws + 38 * MB);
  unsigned short* S   = (unsigned short*)(ws + 46 * MB);
  unsigned short* P   = (unsigned short*)(ws + 0);

  // 1) convert x to bf16
  conv_f32_bf16<<<2048, 256, 0, stream>>>(x, xb, 524288);
  // 2) transpose+convert the three weight matrices
  transconv_w<<<dim3(16, 16, 3), 256, 0, stream>>>(Wq, Wk, Wv, wt);
  // 3) QKV projection: [4096,1024]x[1024,1024] x3, bias fused, bf16 out
  gemm_bt<128, 128, 4, 4, 0><<<dim3(8, 32, 3), 256, 0, stream>>>(
      xb, wt, 1024, 1024, 1024, qkv, 1024,
      (size_t)1048576, (size_t)4194304, bq, bk, bv, 1.0f, nullptr);
  // 4) transpose v -> vt
  trans_bf16<<<dim3(64, 16), 256, 0, stream>>>(vb, vt, 4096, 1024);
  // 4b) zero rsum (vb dead; rsum lives in its tail)
  hipMemsetAsync(rsum, 0, 4096 * sizeof(float), stream);
  // 5) E = exp(q k^T / 32), fused rsum accumulation (max-free: |s| <~ 2)
  gemm_bt<128, 128, 4, 4, 1><<<dim3(32, 32), 256, 0, stream>>>(
      qb, kb, 1024, 1024, 1024, S, 4096,
      (size_t)0, (size_t)0, nullptr, nullptr, nullptr, 0.03125f, rsum);
  // 6) PV split-K x4: P[z] = E[:, z*1024:+1024] @ v[z*1024:+1024, :]
  gemm_bt<128, 128, 4, 4, 2><<<dim3(8, 32, 4), 256, 0, stream>>>(
      S, vt, 4096, 4096, 1024, P, 1024,
      (size_t)0, (size_t)4194304, nullptr, nullptr, nullptr, 1.0f, nullptr);
  // 7) out = (sum_z P[z]) / rsum
  reduce_pv<<<2048, 256, 0, stream>>>(P, rsum, out);
}